// Round 6
// baseline (178.678 us; speedup 1.0000x reference)
//
#include <hip/hip_runtime.h>
#include <math.h>

// Problem constants
#define NN  8
#define CIc 8
#define DIc 8
#define Hh  48
#define Ww  48
#define COo 16
#define DOo 16
#define HW  2304      // 48*48

typedef _Float16 f16x8 __attribute__((ext_vector_type(8)));
typedef _Float16 f16x4 __attribute__((ext_vector_type(4)));
typedef float f32x4 __attribute__((ext_vector_type(4)));

// ---------------- workspace layout (byte offsets) ----------------
// uhat : 37,748,736 f16 =  75,497,472 B   [n,ci,co,p,do]
// b    :  2,359,296 f32 =   9,437,184 B
// bm   :    147,456 f32 =     589,824 B
// is   :    147,456 f32 =     589,824 B
// u16  :  1,384,448 f16 =   2,768,896 B   [n,ci,row52,col52,di]
// w16  :    458,752 f16 =     917,504 B   [ci,co,do,k224]  k = tap*8+di
#define OFFB_UHAT 0
#define OFFB_B    75497472
#define OFFB_BM   84934656
#define OFFB_IS   85524480
#define OFFB_U16  86114304
#define OFFB_W16  88883200

// ---------------------------------------------------- prep u (pad + fp16)
__global__ __launch_bounds__(256) void prep_u_k(const float* __restrict__ u,
                                                _Float16* __restrict__ u16) {
  int idx = blockIdx.x * 256 + threadIdx.x;
  if (idx >= NN * CIc * 52 * 52) return;
  int col = idx % 52;
  int t = idx / 52;
  int row = t % 52;
  t /= 52;                        // t = n*CIc + ci
  int h = row - 2, w = col - 2;
  f16x8 hv;
#pragma unroll
  for (int di = 0; di < 8; ++di) {
    float val = 0.f;
    if (h >= 0 && h < Hh && w >= 0 && w < Ww)
      val = u[((size_t)t * DIc + di) * HW + h * Ww + w];
    hv[di] = (_Float16)val;
  }
  *(f16x8*)(u16 + (size_t)idx * 8) = hv;
}

// ---------------------------------------------------- prep w (reorder + fp16)
// [ci][co][do][k=tap*8+di], taps 25..27 zero-padded.
__global__ __launch_bounds__(256) void prep_w_k(const float* __restrict__ w,
                                                _Float16* __restrict__ w16) {
  int idx = blockIdx.x * 256 + threadIdx.x;
  if (idx >= CIc * COo * DOo * 28) return;
  int tap = idx % 28;
  int t = idx / 28;
  int dd = t % DOo;
  t /= DOo;
  int co = t % COo;
  int ci = t / COo;
  f16x8 hv;
#pragma unroll
  for (int di = 0; di < 8; ++di) {
    float val = 0.f;
    if (tap < 25)
      val = w[((size_t)(ci * 256 + co * 16 + dd)) * 200 + di * 25 + tap];
    hv[di] = (_Float16)val;
  }
  *(f16x8*)(w16 + ((size_t)(ci * COo + co) * DOo + dd) * 224 + tap * 8) = hv;
}

// ---------------------------------------------------------------- MFMA conv
// Per (n,ci): C[256 (co,do), 2304 p] = W[256,224] x im2col(u)[224,2304], pure fp16.
// Block = (n, ci, co-half, pos-eighth): 256 thr / 4 waves; wave = 2 co.
__global__ __launch_bounds__(256, 4) void conv_mfma_k(const _Float16* __restrict__ u16,
                                                      const _Float16* __restrict__ w16,
                                                      _Float16* __restrict__ uhat) {
  __shared__ _Float16 s_u[11 * 52 * 8];   // 9,152 B (row 10 = zeros)

  const int blk = blockIdx.x;
  const int pe = blk & 7;          // pos-eighth: output rows pe*6 .. pe*6+5
  const int ch = (blk >> 3) & 1;   // co half
  const int ci = (blk >> 4) & 7;
  const int n  = blk >> 7;
  const int tid = threadIdx.x;
  const int wv = tid >> 6, lane = tid & 63;
  const int l15 = lane & 15, l4 = lane >> 4;

  const _Float16* gu = u16 + ((size_t)(n * CIc + ci) * 2704 + pe * 6 * 52) * 8;
  for (int it = tid; it < 520; it += 256)
    *(f16x8*)(s_u + it * 8) = *(const f16x8*)(gu + it * 8);
  if (tid < 52) {
    f16x8 z = {0, 0, 0, 0, 0, 0, 0, 0};
    *(f16x8*)(s_u + (520 + tid) * 8) = z;
  }

  const int co0 = ch * 8 + wv * 2;
  f16x8 a[2][7];
#pragma unroll
  for (int c = 0; c < 2; ++c) {
    const _Float16* wb = w16 + ((size_t)(ci * COo + co0 + c) * DOo + l15) * 224 + l4 * 8;
#pragma unroll
    for (int ks = 0; ks < 7; ++ks) a[c][ks] = *(const f16x8*)(wb + ks * 32);
  }
  __syncthreads();

  _Float16* ob = uhat + (size_t)((n * CIc + ci) * COo + co0) * (HW * 16);

  for (int chunk = 0; chunk < 6; ++chunk) {
    f32x4 acc[2][3];
#pragma unroll
    for (int c = 0; c < 2; ++c)
#pragma unroll
      for (int nt = 0; nt < 3; ++nt) {
        f32x4 z = {0.f, 0.f, 0.f, 0.f};
        acc[c][nt] = z;
      }
#pragma unroll
    for (int ks = 0; ks < 7; ++ks) {
      const int tap = ks * 4 + l4;       // 0..27 (25..27: zero weights)
      const int dy = tap / 5;            // 0..5
      const int dx = tap - dy * 5;
      const int row = chunk + dy;        // <= 10
#pragma unroll
      for (int nt = 0; nt < 3; ++nt) {
        const int col = nt * 16 + dx + l15;
        f16x8 bfrag = *(const f16x8*)(s_u + (row * 52 + col) * 8);
        acc[0][nt] = __builtin_amdgcn_mfma_f32_16x16x32_f16(a[0][ks], bfrag, acc[0][nt], 0, 0, 0);
        acc[1][nt] = __builtin_amdgcn_mfma_f32_16x16x32_f16(a[1][ks], bfrag, acc[1][nt], 0, 0, 0);
      }
    }
#pragma unroll
    for (int c = 0; c < 2; ++c)
#pragma unroll
      for (int nt = 0; nt < 3; ++nt) {
        int p = pe * 288 + chunk * 48 + nt * 16 + l15;
        f32x4 vv = acc[c][nt];
        f16x4 hv;
        hv[0] = (_Float16)vv[0]; hv[1] = (_Float16)vv[1];
        hv[2] = (_Float16)vv[2]; hv[3] = (_Float16)vv[3];
        *(f16x4*)(ob + (size_t)c * (HW * 16) + (size_t)p * 16 + l4 * 4) = hv;
      }
  }
}

// ----------------------------------------------------- routing stats (separable)
__global__ __launch_bounds__(256) void routing_stats_k(const float* __restrict__ b,
                                                       float* __restrict__ bmax,
                                                       float* __restrict__ isum,
                                                       int zb) {
  __shared__ float m_lds[HW];
  __shared__ float t_lds[HW];
  const int blk = blockIdx.x;   // n*CIc + ci
  const int tid = threadIdx.x;
  const float* bp = b + (size_t)blk * COo * HW;

  for (int p = tid; p < HW; p += 256) {
    float m;
    if (zb) {
      m = 0.f;
    } else {
      m = -INFINITY;
      for (int co = 0; co < COo; ++co) m = fmaxf(m, bp[(size_t)co * HW + p]);
    }
    m_lds[p] = m;
  }
  __syncthreads();
  for (int p = tid; p < HW; p += 256) {
    int h = p / Ww, w = p % Ww;
    float v = -INFINITY;
#pragma unroll
    for (int dx = -2; dx <= 2; ++dx) {
      int ww2 = w + dx;
      if (ww2 >= 0 && ww2 < Ww) v = fmaxf(v, m_lds[h * Ww + ww2]);
    }
    t_lds[p] = v;
  }
  __syncthreads();
  for (int p = tid; p < HW; p += 256) {
    int h = p / Ww, w = p % Ww;
    float bm = -INFINITY;
#pragma unroll
    for (int dy = -2; dy <= 2; ++dy) {
      int hh = h + dy;
      if (hh >= 0 && hh < Hh) bm = fmaxf(bm, t_lds[hh * Ww + w]);
    }
    bmax[(size_t)blk * HW + p] = bm;
    float cs;
    if (zb) {
      cs = 16.f;
    } else {
      cs = 0.f;
      for (int co = 0; co < COo; ++co)
        cs += __expf(bp[(size_t)co * HW + p] - bm);
    }
    m_lds[p] = cs;
  }
  __syncthreads();
  for (int p = tid; p < HW; p += 256) {
    int h = p / Ww, w = p % Ww;
    float s = 0.f;
#pragma unroll
    for (int dx = -2; dx <= 2; ++dx) {
      int ww2 = w + dx;
      if (ww2 >= 0 && ww2 < Ww) s += m_lds[h * Ww + ww2];
    }
    t_lds[p] = s;
  }
  __syncthreads();
  for (int p = tid; p < HW; p += 256) {
    int h = p / Ww, w = p % Ww;
    float s = 0.f;
#pragma unroll
    for (int dy = -2; dy <= 2; ++dy) {
      int hh = h + dy;
      if (hh >= 0 && hh < Hh) s += t_lds[hh * Ww + w];
    }
    isum[(size_t)blk * HW + p] = 1.f / s;
  }
}

// ------------------------------------------- fused p + squash + b-update
// One thread per (n, co, p). u_hat kept PACKED f16 in regs (64 VGPR), cvt on use.
// All global loads issued upfront; __launch_bounds__(256,4) for 4 waves/SIMD.
__global__ __launch_bounds__(256, 4) void fused_route_k(const float* __restrict__ b,
                                                        const float* __restrict__ bmax,
                                                        const float* __restrict__ isum,
                                                        const _Float16* __restrict__ uhat,
                                                        float* __restrict__ bout,
                                                        float* __restrict__ vout,
                                                        int zb, int last) {
  int idx = blockIdx.x * 256 + threadIdx.x;   // (n*COo+co)*HW + p
  int p  = idx % HW;
  int t  = idx / HW;
  int co = t % COo;
  int n  = t / COo;

  // ---- issue ALL loads upfront (16 uh + 8 bm + 8 is + 8 b)
  f16x8 uh[CIc][2];
#pragma unroll
  for (int ci = 0; ci < CIc; ++ci) {
    const f16x8* uhp = (const f16x8*)(uhat +
        ((size_t)((n * CIc + ci) * COo + co) * HW + p) * DOo);
    uh[ci][0] = uhp[0];
    uh[ci][1] = uhp[1];
  }
  float bmv[CIc], isv[CIc], bl[CIc];
#pragma unroll
  for (int ci = 0; ci < CIc; ++ci) {
    int s = n * CIc + ci;
    bmv[ci] = bmax[(size_t)s * HW + p];
    isv[ci] = isum[(size_t)s * HW + p];
    bl[ci]  = zb ? 0.f : b[(size_t)(s * COo + co) * HW + p];
  }

  float acc[DOo];
#pragma unroll
  for (int d = 0; d < DOo; ++d) acc[d] = 0.f;
#pragma unroll
  for (int ci = 0; ci < CIc; ++ci) {
    float rc = __expf(bl[ci] - bmv[ci]) * isv[ci];
#pragma unroll
    for (int d = 0; d < 8; ++d)
      acc[d] = fmaf(rc, (float)uh[ci][0][d], acc[d]);
#pragma unroll
    for (int d = 0; d < 8; ++d)
      acc[8 + d] = fmaf(rc, (float)uh[ci][1][d], acc[8 + d]);
  }

  float nsq = 0.f;
#pragma unroll
  for (int d = 0; d < DOo; ++d) nsq += acc[d] * acc[d];
  float scale = nsq / (1.f + nsq) / sqrtf(nsq + 1e-9f);
#pragma unroll
  for (int d = 0; d < DOo; ++d) acc[d] *= scale;

  if (last) {
    float* vp = vout + (size_t)(n * COo + co) * DOo * HW + p;
#pragma unroll
    for (int d = 0; d < DOo; ++d) vp[(size_t)d * HW] = acc[d];
  } else {
#pragma unroll
    for (int ci = 0; ci < CIc; ++ci) {
      float dot = 0.f;
#pragma unroll
      for (int d = 0; d < 8; ++d)
        dot = fmaf((float)uh[ci][0][d], acc[d], dot);
#pragma unroll
      for (int d = 0; d < 8; ++d)
        dot = fmaf((float)uh[ci][1][d], acc[8 + d], dot);
      bout[(size_t)((n * CIc + ci) * COo + co) * HW + p] = bl[ci] + dot;
    }
  }
}

// ------------------------------------------------------------------ launch
extern "C" void kernel_launch(void* const* d_in, const int* in_sizes, int n_in,
                              void* d_out, int out_size, void* d_ws, size_t ws_size,
                              hipStream_t stream) {
  const float* u = (const float*)d_in[0];
  const float* w = (const float*)d_in[1];
  float* out = (float*)d_out;
  char* wsb  = (char*)d_ws;

  _Float16*  uhat = (_Float16*)(wsb + OFFB_UHAT);
  float*     b    = (float*)(wsb + OFFB_B);
  float*     bm   = (float*)(wsb + OFFB_BM);
  float*     is   = (float*)(wsb + OFFB_IS);
  _Float16*  u16  = (_Float16*)(wsb + OFFB_U16);
  _Float16*  w16  = (_Float16*)(wsb + OFFB_W16);

  prep_u_k<<<(NN * CIc * 52 * 52 + 255) / 256, 256, 0, stream>>>(u, u16);
  prep_w_k<<<(CIc * COo * DOo * 28 + 255) / 256, 256, 0, stream>>>(w, w16);
  conv_mfma_k<<<NN * CIc * 2 * 8, 256, 0, stream>>>(u16, w16, uhat);

  const int route_grid = (NN * COo * HW) / 256;   // 1152

  routing_stats_k<<<NN * CIc, 256, 0, stream>>>(b, bm, is, 1);
  fused_route_k<<<route_grid, 256, 0, stream>>>(b, bm, is, uhat, b, out, 1, 0);

  routing_stats_k<<<NN * CIc, 256, 0, stream>>>(b, bm, is, 0);
  fused_route_k<<<route_grid, 256, 0, stream>>>(b, bm, is, uhat, b, out, 0, 0);

  routing_stats_k<<<NN * CIc, 256, 0, stream>>>(b, bm, is, 0);
  fused_route_k<<<route_grid, 256, 0, stream>>>(b, bm, is, uhat, b, out, 0, 1);
}

// Round 7
// 169.091 us; speedup vs baseline: 1.0567x; 1.0567x over previous
//
#include <hip/hip_runtime.h>
#include <math.h>

// Problem constants
#define NN  8
#define CIc 8
#define DIc 8
#define Hh  48
#define Ww  48
#define COo 16
#define DOo 16
#define HW  2304      // 48*48

typedef _Float16 f16x8 __attribute__((ext_vector_type(8)));
typedef _Float16 f16x4 __attribute__((ext_vector_type(4)));
typedef float f32x4 __attribute__((ext_vector_type(4)));

// ---------------- workspace layout (byte offsets) ----------------
// uhat : 37,748,736 f16 =  75,497,472 B   [n,ci,co,p,do]
// b    :  2,359,296 f32 =   9,437,184 B
// bm   :    147,456 f32 =     589,824 B
// is   :    147,456 f32 =     589,824 B
// u16  :  1,384,448 f16 =   2,768,896 B   [n,ci,row52,col52,di]
// w16  :    458,752 f16 =     917,504 B   [ci,co,do,k224]  k = tap*8+di
#define OFFB_UHAT 0
#define OFFB_B    75497472
#define OFFB_BM   84934656
#define OFFB_IS   85524480
#define OFFB_U16  86114304
#define OFFB_W16  88883200

// ---------------------------------------------------- prep u (pad + fp16)
__global__ __launch_bounds__(256) void prep_u_k(const float* __restrict__ u,
                                                _Float16* __restrict__ u16) {
  int idx = blockIdx.x * 256 + threadIdx.x;
  if (idx >= NN * CIc * 52 * 52) return;
  int col = idx % 52;
  int t = idx / 52;
  int row = t % 52;
  t /= 52;                        // t = n*CIc + ci
  int h = row - 2, w = col - 2;
  f16x8 hv;
#pragma unroll
  for (int di = 0; di < 8; ++di) {
    float val = 0.f;
    if (h >= 0 && h < Hh && w >= 0 && w < Ww)
      val = u[((size_t)t * DIc + di) * HW + h * Ww + w];
    hv[di] = (_Float16)val;
  }
  *(f16x8*)(u16 + (size_t)idx * 8) = hv;
}

// ---------------------------------------------------- prep w (reorder + fp16)
// [ci][co][do][k=tap*8+di], taps 25..27 zero-padded.
__global__ __launch_bounds__(256) void prep_w_k(const float* __restrict__ w,
                                                _Float16* __restrict__ w16) {
  int idx = blockIdx.x * 256 + threadIdx.x;
  if (idx >= CIc * COo * DOo * 28) return;
  int tap = idx % 28;
  int t = idx / 28;
  int dd = t % DOo;
  t /= DOo;
  int co = t % COo;
  int ci = t / COo;
  f16x8 hv;
#pragma unroll
  for (int di = 0; di < 8; ++di) {
    float val = 0.f;
    if (tap < 25)
      val = w[((size_t)(ci * 256 + co * 16 + dd)) * 200 + di * 25 + tap];
    hv[di] = (_Float16)val;
  }
  *(f16x8*)(w16 + ((size_t)(ci * COo + co) * DOo + dd) * 224 + tap * 8) = hv;
}

// ---------------------------------------------------------------- MFMA conv
// Per (n,ci): C[256 (co,do), 2304 p] = W[256,224] x im2col(u)[224,2304], pure fp16.
// Block = (n, ci, co-half, pos-eighth): 256 thr / 4 waves; wave = 2 co.
__global__ __launch_bounds__(256, 4) void conv_mfma_k(const _Float16* __restrict__ u16,
                                                      const _Float16* __restrict__ w16,
                                                      _Float16* __restrict__ uhat) {
  __shared__ _Float16 s_u[11 * 52 * 8];   // 9,152 B (row 10 = zeros)

  const int blk = blockIdx.x;
  const int pe = blk & 7;          // pos-eighth: output rows pe*6 .. pe*6+5
  const int ch = (blk >> 3) & 1;   // co half
  const int ci = (blk >> 4) & 7;
  const int n  = blk >> 7;
  const int tid = threadIdx.x;
  const int wv = tid >> 6, lane = tid & 63;
  const int l15 = lane & 15, l4 = lane >> 4;

  const _Float16* gu = u16 + ((size_t)(n * CIc + ci) * 2704 + pe * 6 * 52) * 8;
  for (int it = tid; it < 520; it += 256)
    *(f16x8*)(s_u + it * 8) = *(const f16x8*)(gu + it * 8);
  if (tid < 52) {
    f16x8 z = {0, 0, 0, 0, 0, 0, 0, 0};
    *(f16x8*)(s_u + (520 + tid) * 8) = z;
  }

  const int co0 = ch * 8 + wv * 2;
  f16x8 a[2][7];
#pragma unroll
  for (int c = 0; c < 2; ++c) {
    const _Float16* wb = w16 + ((size_t)(ci * COo + co0 + c) * DOo + l15) * 224 + l4 * 8;
#pragma unroll
    for (int ks = 0; ks < 7; ++ks) a[c][ks] = *(const f16x8*)(wb + ks * 32);
  }
  __syncthreads();

  _Float16* ob = uhat + (size_t)((n * CIc + ci) * COo + co0) * (HW * 16);

  for (int chunk = 0; chunk < 6; ++chunk) {
    f32x4 acc[2][3];
#pragma unroll
    for (int c = 0; c < 2; ++c)
#pragma unroll
      for (int nt = 0; nt < 3; ++nt) {
        f32x4 z = {0.f, 0.f, 0.f, 0.f};
        acc[c][nt] = z;
      }
#pragma unroll
    for (int ks = 0; ks < 7; ++ks) {
      const int tap = ks * 4 + l4;       // 0..27 (25..27: zero weights)
      const int dy = tap / 5;            // 0..5
      const int dx = tap - dy * 5;
      const int row = chunk + dy;        // <= 10
#pragma unroll
      for (int nt = 0; nt < 3; ++nt) {
        const int col = nt * 16 + dx + l15;
        f16x8 bfrag = *(const f16x8*)(s_u + (row * 52 + col) * 8);
        acc[0][nt] = __builtin_amdgcn_mfma_f32_16x16x32_f16(a[0][ks], bfrag, acc[0][nt], 0, 0, 0);
        acc[1][nt] = __builtin_amdgcn_mfma_f32_16x16x32_f16(a[1][ks], bfrag, acc[1][nt], 0, 0, 0);
      }
    }
#pragma unroll
    for (int c = 0; c < 2; ++c)
#pragma unroll
      for (int nt = 0; nt < 3; ++nt) {
        int p = pe * 288 + chunk * 48 + nt * 16 + l15;
        f32x4 vv = acc[c][nt];
        f16x4 hv;
        hv[0] = (_Float16)vv[0]; hv[1] = (_Float16)vv[1];
        hv[2] = (_Float16)vv[2]; hv[3] = (_Float16)vv[3];
        *(f16x4*)(ob + (size_t)c * (HW * 16) + (size_t)p * 16 + l4 * 4) = hv;
      }
  }
}

// ----------------------------------------------------- routing stats (separable)
__global__ __launch_bounds__(256) void routing_stats_k(const float* __restrict__ b,
                                                       float* __restrict__ bmax,
                                                       float* __restrict__ isum,
                                                       int zb) {
  __shared__ float m_lds[HW];
  __shared__ float t_lds[HW];
  const int blk = blockIdx.x;   // n*CIc + ci
  const int tid = threadIdx.x;
  const float* bp = b + (size_t)blk * COo * HW;

  for (int p = tid; p < HW; p += 256) {
    float m;
    if (zb) {
      m = 0.f;
    } else {
      m = -INFINITY;
      for (int co = 0; co < COo; ++co) m = fmaxf(m, bp[(size_t)co * HW + p]);
    }
    m_lds[p] = m;
  }
  __syncthreads();
  for (int p = tid; p < HW; p += 256) {
    int h = p / Ww, w = p % Ww;
    float v = -INFINITY;
#pragma unroll
    for (int dx = -2; dx <= 2; ++dx) {
      int ww2 = w + dx;
      if (ww2 >= 0 && ww2 < Ww) v = fmaxf(v, m_lds[h * Ww + ww2]);
    }
    t_lds[p] = v;
  }
  __syncthreads();
  for (int p = tid; p < HW; p += 256) {
    int h = p / Ww, w = p % Ww;
    float bm = -INFINITY;
#pragma unroll
    for (int dy = -2; dy <= 2; ++dy) {
      int hh = h + dy;
      if (hh >= 0 && hh < Hh) bm = fmaxf(bm, t_lds[hh * Ww + w]);
    }
    bmax[(size_t)blk * HW + p] = bm;
    float cs;
    if (zb) {
      cs = 16.f;
    } else {
      cs = 0.f;
      for (int co = 0; co < COo; ++co)
        cs += __expf(bp[(size_t)co * HW + p] - bm);
    }
    m_lds[p] = cs;
  }
  __syncthreads();
  for (int p = tid; p < HW; p += 256) {
    int h = p / Ww, w = p % Ww;
    float s = 0.f;
#pragma unroll
    for (int dx = -2; dx <= 2; ++dx) {
      int ww2 = w + dx;
      if (ww2 >= 0 && ww2 < Ww) s += m_lds[h * Ww + ww2];
    }
    t_lds[p] = s;
  }
  __syncthreads();
  for (int p = tid; p < HW; p += 256) {
    int h = p / Ww, w = p % Ww;
    float s = 0.f;
#pragma unroll
    for (int dy = -2; dy <= 2; ++dy) {
      int hh = h + dy;
      if (hh >= 0 && hh < Hh) s += t_lds[hh * Ww + w];
    }
    isum[(size_t)blk * HW + p] = 1.f / s;
  }
}

// ------------------------------------------- fused p + squash + b-update
// One thread per (n, co, p). Dependency-ordered: scalar loads + rc FIRST
// (sched_barrier fence), then per-ci {uh load; FMA} so each FMA waits only
// on its own loads while later uh loads stay in flight. uh kept packed f16.
__global__ __launch_bounds__(256, 4) void fused_route_k(const float* __restrict__ b,
                                                        const float* __restrict__ bmax,
                                                        const float* __restrict__ isum,
                                                        const _Float16* __restrict__ uhat,
                                                        float* __restrict__ bout,
                                                        float* __restrict__ vout,
                                                        int zb, int last) {
  int idx = blockIdx.x * 256 + threadIdx.x;   // (n*COo+co)*HW + p
  int p  = idx % HW;
  int t  = idx / HW;
  int co = t % COo;
  int n  = t / COo;

  // ---- phase 1: scalar prerequisites -> rc[ci]
  float bl[CIc], rc[CIc];
#pragma unroll
  for (int ci = 0; ci < CIc; ++ci) {
    int s = n * CIc + ci;
    float bm = bmax[(size_t)s * HW + p];
    float is = isum[(size_t)s * HW + p];
    bl[ci] = zb ? 0.f : b[(size_t)(s * COo + co) * HW + p];
    rc[ci] = __expf(bl[ci] - bm) * is;
  }
  __builtin_amdgcn_sched_barrier(0);   // keep uh loads below the rc phase

  // ---- phase 2: stream uh, FMA immediately (loads pipeline ahead)
  f16x8 uh[CIc][2];
  float acc[DOo];
#pragma unroll
  for (int d = 0; d < DOo; ++d) acc[d] = 0.f;
#pragma unroll
  for (int ci = 0; ci < CIc; ++ci) {
    const f16x8* uhp = (const f16x8*)(uhat +
        ((size_t)((n * CIc + ci) * COo + co) * HW + p) * DOo);
    uh[ci][0] = uhp[0];
    uh[ci][1] = uhp[1];
    float r = rc[ci];
#pragma unroll
    for (int d = 0; d < 8; ++d)
      acc[d] = fmaf(r, (float)uh[ci][0][d], acc[d]);
#pragma unroll
    for (int d = 0; d < 8; ++d)
      acc[8 + d] = fmaf(r, (float)uh[ci][1][d], acc[8 + d]);
  }

  float nsq = 0.f;
#pragma unroll
  for (int d = 0; d < DOo; ++d) nsq += acc[d] * acc[d];
  float scale = nsq / (1.f + nsq) / sqrtf(nsq + 1e-9f);
#pragma unroll
  for (int d = 0; d < DOo; ++d) acc[d] *= scale;

  if (last) {
    float* vp = vout + (size_t)(n * COo + co) * DOo * HW + p;
#pragma unroll
    for (int d = 0; d < DOo; ++d) vp[(size_t)d * HW] = acc[d];
  } else {
#pragma unroll
    for (int ci = 0; ci < CIc; ++ci) {
      float dot = 0.f;
#pragma unroll
      for (int d = 0; d < 8; ++d)
        dot = fmaf((float)uh[ci][0][d], acc[d], dot);
#pragma unroll
      for (int d = 0; d < 8; ++d)
        dot = fmaf((float)uh[ci][1][d], acc[8 + d], dot);
      bout[(size_t)((n * CIc + ci) * COo + co) * HW + p] = bl[ci] + dot;
    }
  }
}

// ------------------------------------------------------------------ launch
extern "C" void kernel_launch(void* const* d_in, const int* in_sizes, int n_in,
                              void* d_out, int out_size, void* d_ws, size_t ws_size,
                              hipStream_t stream) {
  const float* u = (const float*)d_in[0];
  const float* w = (const float*)d_in[1];
  float* out = (float*)d_out;
  char* wsb  = (char*)d_ws;

  _Float16*  uhat = (_Float16*)(wsb + OFFB_UHAT);
  float*     b    = (float*)(wsb + OFFB_B);
  float*     bm   = (float*)(wsb + OFFB_BM);
  float*     is   = (float*)(wsb + OFFB_IS);
  _Float16*  u16  = (_Float16*)(wsb + OFFB_U16);
  _Float16*  w16  = (_Float16*)(wsb + OFFB_W16);

  prep_u_k<<<(NN * CIc * 52 * 52 + 255) / 256, 256, 0, stream>>>(u, u16);
  prep_w_k<<<(CIc * COo * DOo * 28 + 255) / 256, 256, 0, stream>>>(w, w16);
  conv_mfma_k<<<NN * CIc * 2 * 8, 256, 0, stream>>>(u16, w16, uhat);

  const int route_grid = (NN * COo * HW) / 256;   // 1152

  routing_stats_k<<<NN * CIc, 256, 0, stream>>>(b, bm, is, 1);
  fused_route_k<<<route_grid, 256, 0, stream>>>(b, bm, is, uhat, b, out, 1, 0);

  routing_stats_k<<<NN * CIc, 256, 0, stream>>>(b, bm, is, 0);
  fused_route_k<<<route_grid, 256, 0, stream>>>(b, bm, is, uhat, b, out, 0, 0);

  routing_stats_k<<<NN * CIc, 256, 0, stream>>>(b, bm, is, 0);
  fused_route_k<<<route_grid, 256, 0, stream>>>(b, bm, is, uhat, b, out, 0, 1);
}

// Round 8
// 127.609 us; speedup vs baseline: 1.4002x; 1.3251x over previous
//
#include <hip/hip_runtime.h>
#include <math.h>

// Problem constants
#define NN  8
#define CIc 8
#define DIc 8
#define Hh  48
#define Ww  48
#define COo 16
#define DOo 16
#define HW  2304      // 48*48

typedef _Float16 f16x8 __attribute__((ext_vector_type(8)));
typedef _Float16 f16x4 __attribute__((ext_vector_type(4)));
typedef float f32x4 __attribute__((ext_vector_type(4)));

// ---------------- workspace layout (byte offsets) ----------------
// uhat : 37,748,736 f16 =  75,497,472 B   [n,ci,co,p,do]
// b    :  2,359,296 f32 =   9,437,184 B
// bm   :    147,456 f32 =     589,824 B
// is   :    147,456 f32 =     589,824 B
// u16  :  1,384,448 f16 =   2,768,896 B   [n,ci,row52,col52,di]
// w16  :    458,752 f16 =     917,504 B   [ci,co,do,k224]  k = tap*8+di
#define OFFB_UHAT 0
#define OFFB_B    75497472
#define OFFB_BM   84934656
#define OFFB_IS   85524480
#define OFFB_U16  86114304
#define OFFB_W16  88883200

#define PREP_U_BLOCKS 676    // 8*8*52*52 / 256
#define PREP_W_BLOCKS 224    // 8*16*16*28 / 256

// -------------------------------------- merged prep (u pad+fp16 | w reorder+fp16)
__global__ __launch_bounds__(256) void prep_k(const float* __restrict__ u,
                                              const float* __restrict__ w,
                                              _Float16* __restrict__ u16,
                                              _Float16* __restrict__ w16) {
  if (blockIdx.x < PREP_U_BLOCKS) {
    int idx = blockIdx.x * 256 + threadIdx.x;
    int col = idx % 52;
    int t = idx / 52;
    int row = t % 52;
    t /= 52;                        // t = n*CIc + ci
    int h = row - 2, wc = col - 2;
    f16x8 hv;
#pragma unroll
    for (int di = 0; di < 8; ++di) {
      float val = 0.f;
      if (h >= 0 && h < Hh && wc >= 0 && wc < Ww)
        val = u[((size_t)t * DIc + di) * HW + h * Ww + wc];
      hv[di] = (_Float16)val;
    }
    *(f16x8*)(u16 + (size_t)idx * 8) = hv;
  } else {
    int idx = (blockIdx.x - PREP_U_BLOCKS) * 256 + threadIdx.x;
    int tap = idx % 28;
    int t = idx / 28;
    int dd = t % DOo;
    t /= DOo;
    int co = t % COo;
    int ci = t / COo;
    f16x8 hv;
#pragma unroll
    for (int di = 0; di < 8; ++di) {
      float val = 0.f;
      if (tap < 25)
        val = w[((size_t)(ci * 256 + co * 16 + dd)) * 200 + di * 25 + tap];
      hv[di] = (_Float16)val;
    }
    *(f16x8*)(w16 + ((size_t)(ci * COo + co) * DOo + dd) * 224 + tap * 8) = hv;
  }
}

// ---------------------------------------------------------------- MFMA conv
// Per (n,ci): C[256 (co,do), 2304 p] = W[256,224] x im2col(u)[224,2304], pure fp16.
// Block = (n, ci, co-half, pos-eighth): 256 thr / 4 waves; wave = 2 co.
__global__ __launch_bounds__(256, 4) void conv_mfma_k(const _Float16* __restrict__ u16,
                                                      const _Float16* __restrict__ w16,
                                                      _Float16* __restrict__ uhat) {
  __shared__ _Float16 s_u[11 * 52 * 8];   // 9,152 B (row 10 = zeros)

  const int blk = blockIdx.x;
  const int pe = blk & 7;          // pos-eighth: output rows pe*6 .. pe*6+5
  const int ch = (blk >> 3) & 1;   // co half
  const int ci = (blk >> 4) & 7;
  const int n  = blk >> 7;
  const int tid = threadIdx.x;
  const int wv = tid >> 6, lane = tid & 63;
  const int l15 = lane & 15, l4 = lane >> 4;

  const _Float16* gu = u16 + ((size_t)(n * CIc + ci) * 2704 + pe * 6 * 52) * 8;
  for (int it = tid; it < 520; it += 256)
    *(f16x8*)(s_u + it * 8) = *(const f16x8*)(gu + it * 8);
  if (tid < 52) {
    f16x8 z = {0, 0, 0, 0, 0, 0, 0, 0};
    *(f16x8*)(s_u + (520 + tid) * 8) = z;
  }

  const int co0 = ch * 8 + wv * 2;
  f16x8 a[2][7];
#pragma unroll
  for (int c = 0; c < 2; ++c) {
    const _Float16* wb = w16 + ((size_t)(ci * COo + co0 + c) * DOo + l15) * 224 + l4 * 8;
#pragma unroll
    for (int ks = 0; ks < 7; ++ks) a[c][ks] = *(const f16x8*)(wb + ks * 32);
  }
  __syncthreads();

  _Float16* ob = uhat + (size_t)((n * CIc + ci) * COo + co0) * (HW * 16);

  for (int chunk = 0; chunk < 6; ++chunk) {
    f32x4 acc[2][3];
#pragma unroll
    for (int c = 0; c < 2; ++c)
#pragma unroll
      for (int nt = 0; nt < 3; ++nt) {
        f32x4 z = {0.f, 0.f, 0.f, 0.f};
        acc[c][nt] = z;
      }
#pragma unroll
    for (int ks = 0; ks < 7; ++ks) {
      const int tap = ks * 4 + l4;       // 0..27 (25..27: zero weights)
      const int dy = tap / 5;            // 0..5
      const int dx = tap - dy * 5;
      const int row = chunk + dy;        // <= 10
#pragma unroll
      for (int nt = 0; nt < 3; ++nt) {
        const int col = nt * 16 + dx + l15;
        f16x8 bfrag = *(const f16x8*)(s_u + (row * 52 + col) * 8);
        acc[0][nt] = __builtin_amdgcn_mfma_f32_16x16x32_f16(a[0][ks], bfrag, acc[0][nt], 0, 0, 0);
        acc[1][nt] = __builtin_amdgcn_mfma_f32_16x16x32_f16(a[1][ks], bfrag, acc[1][nt], 0, 0, 0);
      }
    }
#pragma unroll
    for (int c = 0; c < 2; ++c)
#pragma unroll
      for (int nt = 0; nt < 3; ++nt) {
        int p = pe * 288 + chunk * 48 + nt * 16 + l15;
        f32x4 vv = acc[c][nt];
        f16x4 hv;
        hv[0] = (_Float16)vv[0]; hv[1] = (_Float16)vv[1];
        hv[2] = (_Float16)vv[2]; hv[3] = (_Float16)vv[3];
        *(f16x4*)(ob + (size_t)c * (HW * 16) + (size_t)p * 16 + l4 * 4) = hv;
      }
  }
}

// ----------------------------------------------------- routing stats (separable)
__global__ __launch_bounds__(256) void routing_stats_k(const float* __restrict__ b,
                                                       float* __restrict__ bmax,
                                                       float* __restrict__ isum,
                                                       int zb) {
  __shared__ float m_lds[HW];
  __shared__ float t_lds[HW];
  const int blk = blockIdx.x;   // n*CIc + ci
  const int tid = threadIdx.x;
  const float* bp = b + (size_t)blk * COo * HW;

  for (int p = tid; p < HW; p += 256) {
    float m;
    if (zb) {
      m = 0.f;
    } else {
      m = -INFINITY;
      for (int co = 0; co < COo; ++co) m = fmaxf(m, bp[(size_t)co * HW + p]);
    }
    m_lds[p] = m;
  }
  __syncthreads();
  for (int p = tid; p < HW; p += 256) {
    int h = p / Ww, w = p % Ww;
    float v = -INFINITY;
#pragma unroll
    for (int dx = -2; dx <= 2; ++dx) {
      int ww2 = w + dx;
      if (ww2 >= 0 && ww2 < Ww) v = fmaxf(v, m_lds[h * Ww + ww2]);
    }
    t_lds[p] = v;
  }
  __syncthreads();
  for (int p = tid; p < HW; p += 256) {
    int h = p / Ww, w = p % Ww;
    float bm = -INFINITY;
#pragma unroll
    for (int dy = -2; dy <= 2; ++dy) {
      int hh = h + dy;
      if (hh >= 0 && hh < Hh) bm = fmaxf(bm, t_lds[hh * Ww + w]);
    }
    bmax[(size_t)blk * HW + p] = bm;
    float cs;
    if (zb) {
      cs = 16.f;
    } else {
      cs = 0.f;
      for (int co = 0; co < COo; ++co)
        cs += __expf(bp[(size_t)co * HW + p] - bm);
    }
    m_lds[p] = cs;
  }
  __syncthreads();
  for (int p = tid; p < HW; p += 256) {
    int h = p / Ww, w = p % Ww;
    float s = 0.f;
#pragma unroll
    for (int dx = -2; dx <= 2; ++dx) {
      int ww2 = w + dx;
      if (ww2 >= 0 && ww2 < Ww) s += m_lds[h * Ww + ww2];
    }
    t_lds[p] = s;
  }
  __syncthreads();
  for (int p = tid; p < HW; p += 256) {
    int h = p / Ww, w = p % Ww;
    float s = 0.f;
#pragma unroll
    for (int dy = -2; dy <= 2; ++dy) {
      int hh = h + dy;
      if (hh >= 0 && hh < Hh) s += t_lds[hh * Ww + w];
    }
    isum[(size_t)blk * HW + p] = 1.f / s;
  }
}

// ------------------------------------------- fused p + squash + b-update
// R5-exact codegen pattern: uh converted to LIVE f32 registers at load
// (deep load pipelining), __launch_bounds__(256,2). Proven-fast config.
__global__ __launch_bounds__(256, 2) void fused_route_k(const float* __restrict__ b,
                                                        const float* __restrict__ bmax,
                                                        const float* __restrict__ isum,
                                                        const _Float16* __restrict__ uhat,
                                                        float* __restrict__ bout,
                                                        float* __restrict__ vout,
                                                        int zb, int last) {
  int idx = blockIdx.x * 256 + threadIdx.x;   // (n*COo+co)*HW + p
  int p  = idx % HW;
  int t  = idx / HW;
  int co = t % COo;
  int n  = t / COo;

  float bl[CIc], r[CIc];
#pragma unroll
  for (int ci = 0; ci < CIc; ++ci) {
    int s = n * CIc + ci;
    bl[ci] = zb ? 0.f : b[(size_t)(s * COo + co) * HW + p];
    r[ci]  = __expf(bl[ci] - bmax[(size_t)s * HW + p]) * isum[(size_t)s * HW + p];
  }

  float4 uh[CIc][4];
  float4 a0 = make_float4(0.f, 0.f, 0.f, 0.f);
  float4 a1 = a0, a2 = a0, a3 = a0;
#pragma unroll
  for (int ci = 0; ci < CIc; ++ci) {
    const f16x8* uhp = (const f16x8*)(uhat +
        ((size_t)((n * CIc + ci) * COo + co) * HW + p) * DOo);
    f16x8 h0 = uhp[0], h1 = uhp[1];
    uh[ci][0] = make_float4((float)h0[0], (float)h0[1], (float)h0[2], (float)h0[3]);
    uh[ci][1] = make_float4((float)h0[4], (float)h0[5], (float)h0[6], (float)h0[7]);
    uh[ci][2] = make_float4((float)h1[0], (float)h1[1], (float)h1[2], (float)h1[3]);
    uh[ci][3] = make_float4((float)h1[4], (float)h1[5], (float)h1[6], (float)h1[7]);
    float rc = r[ci];
    a0.x = fmaf(rc, uh[ci][0].x, a0.x); a0.y = fmaf(rc, uh[ci][0].y, a0.y);
    a0.z = fmaf(rc, uh[ci][0].z, a0.z); a0.w = fmaf(rc, uh[ci][0].w, a0.w);
    a1.x = fmaf(rc, uh[ci][1].x, a1.x); a1.y = fmaf(rc, uh[ci][1].y, a1.y);
    a1.z = fmaf(rc, uh[ci][1].z, a1.z); a1.w = fmaf(rc, uh[ci][1].w, a1.w);
    a2.x = fmaf(rc, uh[ci][2].x, a2.x); a2.y = fmaf(rc, uh[ci][2].y, a2.y);
    a2.z = fmaf(rc, uh[ci][2].z, a2.z); a2.w = fmaf(rc, uh[ci][2].w, a2.w);
    a3.x = fmaf(rc, uh[ci][3].x, a3.x); a3.y = fmaf(rc, uh[ci][3].y, a3.y);
    a3.z = fmaf(rc, uh[ci][3].z, a3.z); a3.w = fmaf(rc, uh[ci][3].w, a3.w);
  }

  float nsq = a0.x*a0.x + a0.y*a0.y + a0.z*a0.z + a0.w*a0.w
            + a1.x*a1.x + a1.y*a1.y + a1.z*a1.z + a1.w*a1.w
            + a2.x*a2.x + a2.y*a2.y + a2.z*a2.z + a2.w*a2.w
            + a3.x*a3.x + a3.y*a3.y + a3.z*a3.z + a3.w*a3.w;
  float scale = nsq / (1.f + nsq) / sqrtf(nsq + 1e-9f);
  a0.x *= scale; a0.y *= scale; a0.z *= scale; a0.w *= scale;
  a1.x *= scale; a1.y *= scale; a1.z *= scale; a1.w *= scale;
  a2.x *= scale; a2.y *= scale; a2.z *= scale; a2.w *= scale;
  a3.x *= scale; a3.y *= scale; a3.z *= scale; a3.w *= scale;

  if (last) {
    float* vp = vout + (size_t)(n * COo + co) * DOo * HW + p;
    vp[0*HW]=a0.x; vp[1*HW]=a0.y; vp[2*HW]=a0.z; vp[3*HW]=a0.w;
    vp[4*HW]=a1.x; vp[5*HW]=a1.y; vp[6*HW]=a1.z; vp[7*HW]=a1.w;
    vp[8*HW]=a2.x; vp[9*HW]=a2.y; vp[10*HW]=a2.z; vp[11*HW]=a2.w;
    vp[12*HW]=a3.x; vp[13*HW]=a3.y; vp[14*HW]=a3.z; vp[15*HW]=a3.w;
  } else {
#pragma unroll
    for (int ci = 0; ci < CIc; ++ci) {
      float dot = uh[ci][0].x*a0.x + uh[ci][0].y*a0.y + uh[ci][0].z*a0.z + uh[ci][0].w*a0.w
                + uh[ci][1].x*a1.x + uh[ci][1].y*a1.y + uh[ci][1].z*a1.z + uh[ci][1].w*a1.w
                + uh[ci][2].x*a2.x + uh[ci][2].y*a2.y + uh[ci][2].z*a2.z + uh[ci][2].w*a2.w
                + uh[ci][3].x*a3.x + uh[ci][3].y*a3.y + uh[ci][3].z*a3.z + uh[ci][3].w*a3.w;
      bout[(size_t)((n * CIc + ci) * COo + co) * HW + p] = bl[ci] + dot;
    }
  }
}

// ------------------------------------------------------------------ launch
extern "C" void kernel_launch(void* const* d_in, const int* in_sizes, int n_in,
                              void* d_out, int out_size, void* d_ws, size_t ws_size,
                              hipStream_t stream) {
  const float* u = (const float*)d_in[0];
  const float* w = (const float*)d_in[1];
  float* out = (float*)d_out;
  char* wsb  = (char*)d_ws;

  _Float16*  uhat = (_Float16*)(wsb + OFFB_UHAT);
  float*     b    = (float*)(wsb + OFFB_B);
  float*     bm   = (float*)(wsb + OFFB_BM);
  float*     is   = (float*)(wsb + OFFB_IS);
  _Float16*  u16  = (_Float16*)(wsb + OFFB_U16);
  _Float16*  w16  = (_Float16*)(wsb + OFFB_W16);

  prep_k<<<PREP_U_BLOCKS + PREP_W_BLOCKS, 256, 0, stream>>>(u, w, u16, w16);
  conv_mfma_k<<<NN * CIc * 2 * 8, 256, 0, stream>>>(u16, w16, uhat);

  const int route_grid = (NN * COo * HW) / 256;   // 1152

  routing_stats_k<<<NN * CIc, 256, 0, stream>>>(b, bm, is, 1);
  fused_route_k<<<route_grid, 256, 0, stream>>>(b, bm, is, uhat, b, out, 1, 0);

  routing_stats_k<<<NN * CIc, 256, 0, stream>>>(b, bm, is, 0);
  fused_route_k<<<route_grid, 256, 0, stream>>>(b, bm, is, uhat, b, out, 0, 0);

  routing_stats_k<<<NN * CIc, 256, 0, stream>>>(b, bm, is, 0);
  fused_route_k<<<route_grid, 256, 0, stream>>>(b, bm, is, uhat, b, out, 0, 1);
}

// Round 9
// 112.320 us; speedup vs baseline: 1.5908x; 1.1361x over previous
//
#include <hip/hip_runtime.h>
#include <math.h>

// Problem constants
#define NN  8
#define CIc 8
#define DIc 8
#define Hh  48
#define Ww  48
#define COo 16
#define DOo 16
#define HW  2304      // 48*48

typedef _Float16 f16x8 __attribute__((ext_vector_type(8)));
typedef _Float16 f16x4 __attribute__((ext_vector_type(4)));
typedef float f32x4 __attribute__((ext_vector_type(4)));

// ---------------- workspace layout (byte offsets) ----------------
// uhat : 37,748,736 f16 =  75,497,472 B   [n,ci,co,p,do]
// b    :  2,359,296 f32 =   9,437,184 B
// bm   :    147,456 f32 =     589,824 B
// is   :    147,456 f32 =     589,824 B
// u16  :  1,384,448 f16 =   2,768,896 B   [n,ci,row52,col52,di]
// w16  :    458,752 f16 =     917,504 B   [ci,co,do,k224]  k = tap*8+di
#define OFFB_UHAT 0
#define OFFB_B    75497472
#define OFFB_BM   84934656
#define OFFB_IS   85524480
#define OFFB_U16  86114304
#define OFFB_W16  88883200

#define PREP_U_BLOCKS 676    // 8*8*52*52 / 256
#define PREP_W_BLOCKS 224    // 8*16*16*28 / 256

// -------------------------------------- merged prep (u pad+fp16 | w reorder+fp16)
__global__ __launch_bounds__(256) void prep_k(const float* __restrict__ u,
                                              const float* __restrict__ w,
                                              _Float16* __restrict__ u16,
                                              _Float16* __restrict__ w16) {
  if (blockIdx.x < PREP_U_BLOCKS) {
    int idx = blockIdx.x * 256 + threadIdx.x;
    int col = idx % 52;
    int t = idx / 52;
    int row = t % 52;
    t /= 52;                        // t = n*CIc + ci
    int h = row - 2, wc = col - 2;
    f16x8 hv;
#pragma unroll
    for (int di = 0; di < 8; ++di) {
      float val = 0.f;
      if (h >= 0 && h < Hh && wc >= 0 && wc < Ww)
        val = u[((size_t)t * DIc + di) * HW + h * Ww + wc];
      hv[di] = (_Float16)val;
    }
    *(f16x8*)(u16 + (size_t)idx * 8) = hv;
  } else {
    int idx = (blockIdx.x - PREP_U_BLOCKS) * 256 + threadIdx.x;
    int tap = idx % 28;
    int t = idx / 28;
    int dd = t % DOo;
    t /= DOo;
    int co = t % COo;
    int ci = t / COo;
    f16x8 hv;
#pragma unroll
    for (int di = 0; di < 8; ++di) {
      float val = 0.f;
      if (tap < 25)
        val = w[((size_t)(ci * 256 + co * 16 + dd)) * 200 + di * 25 + tap];
      hv[di] = (_Float16)val;
    }
    *(f16x8*)(w16 + ((size_t)(ci * COo + co) * DOo + dd) * 224 + tap * 8) = hv;
  }
}

// ---------------------------------------------------------------- MFMA conv
// Per (n,ci): C[256 (co,do), 2304 p] = W[256,224] x im2col(u)[224,2304], pure fp16.
// Block = (n, ci, co-half, pos-eighth): 256 thr / 4 waves; wave = 2 co.
__global__ __launch_bounds__(256, 4) void conv_mfma_k(const _Float16* __restrict__ u16,
                                                      const _Float16* __restrict__ w16,
                                                      _Float16* __restrict__ uhat) {
  __shared__ _Float16 s_u[11 * 52 * 8];   // 9,152 B (row 10 = zeros)

  const int blk = blockIdx.x;
  const int pe = blk & 7;          // pos-eighth: output rows pe*6 .. pe*6+5
  const int ch = (blk >> 3) & 1;   // co half
  const int ci = (blk >> 4) & 7;
  const int n  = blk >> 7;
  const int tid = threadIdx.x;
  const int wv = tid >> 6, lane = tid & 63;
  const int l15 = lane & 15, l4 = lane >> 4;

  const _Float16* gu = u16 + ((size_t)(n * CIc + ci) * 2704 + pe * 6 * 52) * 8;
  for (int it = tid; it < 520; it += 256)
    *(f16x8*)(s_u + it * 8) = *(const f16x8*)(gu + it * 8);
  if (tid < 52) {
    f16x8 z = {0, 0, 0, 0, 0, 0, 0, 0};
    *(f16x8*)(s_u + (520 + tid) * 8) = z;
  }

  const int co0 = ch * 8 + wv * 2;
  f16x8 a[2][7];
#pragma unroll
  for (int c = 0; c < 2; ++c) {
    const _Float16* wb = w16 + ((size_t)(ci * COo + co0 + c) * DOo + l15) * 224 + l4 * 8;
#pragma unroll
    for (int ks = 0; ks < 7; ++ks) a[c][ks] = *(const f16x8*)(wb + ks * 32);
  }
  __syncthreads();

  _Float16* ob = uhat + (size_t)((n * CIc + ci) * COo + co0) * (HW * 16);

  for (int chunk = 0; chunk < 6; ++chunk) {
    f32x4 acc[2][3];
#pragma unroll
    for (int c = 0; c < 2; ++c)
#pragma unroll
      for (int nt = 0; nt < 3; ++nt) {
        f32x4 z = {0.f, 0.f, 0.f, 0.f};
        acc[c][nt] = z;
      }
#pragma unroll
    for (int ks = 0; ks < 7; ++ks) {
      const int tap = ks * 4 + l4;       // 0..27 (25..27: zero weights)
      const int dy = tap / 5;            // 0..5
      const int dx = tap - dy * 5;
      const int row = chunk + dy;        // <= 10
#pragma unroll
      for (int nt = 0; nt < 3; ++nt) {
        const int col = nt * 16 + dx + l15;
        f16x8 bfrag = *(const f16x8*)(s_u + (row * 52 + col) * 8);
        acc[0][nt] = __builtin_amdgcn_mfma_f32_16x16x32_f16(a[0][ks], bfrag, acc[0][nt], 0, 0, 0);
        acc[1][nt] = __builtin_amdgcn_mfma_f32_16x16x32_f16(a[1][ks], bfrag, acc[1][nt], 0, 0, 0);
      }
    }
#pragma unroll
    for (int c = 0; c < 2; ++c)
#pragma unroll
      for (int nt = 0; nt < 3; ++nt) {
        int p = pe * 288 + chunk * 48 + nt * 16 + l15;
        f32x4 vv = acc[c][nt];
        f16x4 hv;
        hv[0] = (_Float16)vv[0]; hv[1] = (_Float16)vv[1];
        hv[2] = (_Float16)vv[2]; hv[3] = (_Float16)vv[3];
        *(f16x4*)(ob + (size_t)c * (HW * 16) + (size_t)p * 16 + l4 * 4) = hv;
      }
  }
}

// ----------------------------------------------------- routing stats (separable)
__global__ __launch_bounds__(256) void routing_stats_k(const float* __restrict__ b,
                                                       float* __restrict__ bmax,
                                                       float* __restrict__ isum) {
  __shared__ float m_lds[HW];
  __shared__ float t_lds[HW];
  const int blk = blockIdx.x;   // n*CIc + ci
  const int tid = threadIdx.x;
  const float* bp = b + (size_t)blk * COo * HW;

  for (int p = tid; p < HW; p += 256) {
    float m = -INFINITY;
    for (int co = 0; co < COo; ++co) m = fmaxf(m, bp[(size_t)co * HW + p]);
    m_lds[p] = m;
  }
  __syncthreads();
  for (int p = tid; p < HW; p += 256) {
    int h = p / Ww, w = p % Ww;
    float v = -INFINITY;
#pragma unroll
    for (int dx = -2; dx <= 2; ++dx) {
      int ww2 = w + dx;
      if (ww2 >= 0 && ww2 < Ww) v = fmaxf(v, m_lds[h * Ww + ww2]);
    }
    t_lds[p] = v;
  }
  __syncthreads();
  for (int p = tid; p < HW; p += 256) {
    int h = p / Ww, w = p % Ww;
    float bm = -INFINITY;
#pragma unroll
    for (int dy = -2; dy <= 2; ++dy) {
      int hh = h + dy;
      if (hh >= 0 && hh < Hh) bm = fmaxf(bm, t_lds[hh * Ww + w]);
    }
    bmax[(size_t)blk * HW + p] = bm;
    float cs = 0.f;
    for (int co = 0; co < COo; ++co)
      cs += __expf(bp[(size_t)co * HW + p] - bm);
    m_lds[p] = cs;
  }
  __syncthreads();
  for (int p = tid; p < HW; p += 256) {
    int h = p / Ww, w = p % Ww;
    float s = 0.f;
#pragma unroll
    for (int dx = -2; dx <= 2; ++dx) {
      int ww2 = w + dx;
      if (ww2 >= 0 && ww2 < Ww) s += m_lds[h * Ww + ww2];
    }
    t_lds[p] = s;
  }
  __syncthreads();
  for (int p = tid; p < HW; p += 256) {
    int h = p / Ww, w = p % Ww;
    float s = 0.f;
#pragma unroll
    for (int dy = -2; dy <= 2; ++dy) {
      int hh = h + dy;
      if (hh >= 0 && hh < Hh) s += t_lds[hh * Ww + w];
    }
    isum[(size_t)blk * HW + p] = 1.f / s;
  }
}

// ------------------------------------------- fused p + squash + b-update
// Lane-pair split: thread handles 8 of 16 do (half = idx&1); pair cooperates
// via __shfl_xor(.,1) for nsq and the b-dot. uh cvt to LIVE f32 at load
// (proven-fast codegen pattern). d0 (zb=1): r = 1/(16*valid(p)) closed-form,
// no b/bmax/isum loads at all.
__global__ __launch_bounds__(256, 4) void fused_route_k(const float* __restrict__ b,
                                                        const float* __restrict__ bmax,
                                                        const float* __restrict__ isum,
                                                        const _Float16* __restrict__ uhat,
                                                        float* __restrict__ bout,
                                                        float* __restrict__ vout,
                                                        int zb, int last) {
  int idx  = blockIdx.x * 256 + threadIdx.x;  // (((n*COo+co)*HW)+p)*2 + half
  int half = idx & 1;
  int t0   = idx >> 1;
  int p  = t0 % HW;
  int t  = t0 / HW;
  int co = t % COo;
  int n  = t / COo;

  float bl[CIc], r[CIc];
  if (zb) {
    int h = p / Ww, w = p % Ww;
    int ch = min(h + 2, Hh - 1) - max(h - 2, 0) + 1;
    int cw = min(w + 2, Ww - 1) - max(w - 2, 0) + 1;
    float r0 = 1.f / (16.f * (float)(ch * cw));
#pragma unroll
    for (int ci = 0; ci < CIc; ++ci) { bl[ci] = 0.f; r[ci] = r0; }
  } else {
#pragma unroll
    for (int ci = 0; ci < CIc; ++ci) {
      int s = n * CIc + ci;
      bl[ci] = b[(size_t)(s * COo + co) * HW + p];
      r[ci]  = __expf(bl[ci] - bmax[(size_t)s * HW + p]) * isum[(size_t)s * HW + p];
    }
  }

  // 8 do per thread (half selects the f16x8 chunk); cvt to live f32 regs.
  float4 uh[CIc][2];
  float4 a0 = make_float4(0.f, 0.f, 0.f, 0.f);
  float4 a1 = a0;
#pragma unroll
  for (int ci = 0; ci < CIc; ++ci) {
    const f16x8* uhp = (const f16x8*)(uhat +
        ((size_t)((n * CIc + ci) * COo + co) * HW + p) * DOo + half * 8);
    f16x8 h0 = uhp[0];
    uh[ci][0] = make_float4((float)h0[0], (float)h0[1], (float)h0[2], (float)h0[3]);
    uh[ci][1] = make_float4((float)h0[4], (float)h0[5], (float)h0[6], (float)h0[7]);
    float rc = r[ci];
    a0.x = fmaf(rc, uh[ci][0].x, a0.x); a0.y = fmaf(rc, uh[ci][0].y, a0.y);
    a0.z = fmaf(rc, uh[ci][0].z, a0.z); a0.w = fmaf(rc, uh[ci][0].w, a0.w);
    a1.x = fmaf(rc, uh[ci][1].x, a1.x); a1.y = fmaf(rc, uh[ci][1].y, a1.y);
    a1.z = fmaf(rc, uh[ci][1].z, a1.z); a1.w = fmaf(rc, uh[ci][1].w, a1.w);
  }

  float nsqp = a0.x*a0.x + a0.y*a0.y + a0.z*a0.z + a0.w*a0.w
             + a1.x*a1.x + a1.y*a1.y + a1.z*a1.z + a1.w*a1.w;
  float nsq = nsqp + __shfl_xor(nsqp, 1);
  float scale = nsq / (1.f + nsq) / sqrtf(nsq + 1e-9f);
  a0.x *= scale; a0.y *= scale; a0.z *= scale; a0.w *= scale;
  a1.x *= scale; a1.y *= scale; a1.z *= scale; a1.w *= scale;

  if (last) {
    float* vp = vout + (size_t)(n * COo + co) * DOo * HW + (size_t)half * 8 * HW + p;
    vp[0*HW]=a0.x; vp[1*HW]=a0.y; vp[2*HW]=a0.z; vp[3*HW]=a0.w;
    vp[4*HW]=a1.x; vp[5*HW]=a1.y; vp[6*HW]=a1.z; vp[7*HW]=a1.w;
  } else {
#pragma unroll
    for (int ci = 0; ci < CIc; ++ci) {
      float dp = uh[ci][0].x*a0.x + uh[ci][0].y*a0.y + uh[ci][0].z*a0.z + uh[ci][0].w*a0.w
               + uh[ci][1].x*a1.x + uh[ci][1].y*a1.y + uh[ci][1].z*a1.z + uh[ci][1].w*a1.w;
      float dot = dp + __shfl_xor(dp, 1);
      if (half == 0)
        bout[(size_t)((n * CIc + ci) * COo + co) * HW + p] = bl[ci] + dot;
    }
  }
}

// ------------------------------------------------------------------ launch
extern "C" void kernel_launch(void* const* d_in, const int* in_sizes, int n_in,
                              void* d_out, int out_size, void* d_ws, size_t ws_size,
                              hipStream_t stream) {
  const float* u = (const float*)d_in[0];
  const float* w = (const float*)d_in[1];
  float* out = (float*)d_out;
  char* wsb  = (char*)d_ws;

  _Float16*  uhat = (_Float16*)(wsb + OFFB_UHAT);
  float*     b    = (float*)(wsb + OFFB_B);
  float*     bm   = (float*)(wsb + OFFB_BM);
  float*     is   = (float*)(wsb + OFFB_IS);
  _Float16*  u16  = (_Float16*)(wsb + OFFB_U16);
  _Float16*  w16  = (_Float16*)(wsb + OFFB_W16);

  prep_k<<<PREP_U_BLOCKS + PREP_W_BLOCKS, 256, 0, stream>>>(u, w, u16, w16);
  conv_mfma_k<<<NN * CIc * 2 * 8, 256, 0, stream>>>(u16, w16, uhat);

  const int route_grid = (NN * COo * HW * 2) / 256;   // 2304

  // d = 0: closed-form r, no stats dispatch
  fused_route_k<<<route_grid, 256, 0, stream>>>(b, bm, is, uhat, b, out, 1, 0);

  // d = 1
  routing_stats_k<<<NN * CIc, 256, 0, stream>>>(b, bm, is);
  fused_route_k<<<route_grid, 256, 0, stream>>>(b, bm, is, uhat, b, out, 0, 0);

  // d = 2 -> final v straight to d_out
  routing_stats_k<<<NN * CIc, 256, 0, stream>>>(b, bm, is);
  fused_route_k<<<route_grid, 256, 0, stream>>>(b, bm, is, uhat, b, out, 0, 1);
}

// Round 10
// 110.546 us; speedup vs baseline: 1.6163x; 1.0160x over previous
//
#include <hip/hip_runtime.h>
#include <math.h>

// Problem constants
#define NN  8
#define CIc 8
#define DIc 8
#define Hh  48
#define Ww  48
#define COo 16
#define DOo 16
#define HW  2304      // 48*48

typedef _Float16 f16x8 __attribute__((ext_vector_type(8)));
typedef _Float16 f16x4 __attribute__((ext_vector_type(4)));
typedef float f32x4 __attribute__((ext_vector_type(4)));

// ---------------- workspace layout (byte offsets) ----------------
#define OFFB_UHAT 0
#define OFFB_B    75497472
#define OFFB_BM   84934656
#define OFFB_IS   85524480
#define OFFB_U16  86114304
#define OFFB_W16  88883200

#define PREP_U_BLOCKS 676    // 8*8*52*52 / 256
#define PREP_W_BLOCKS 224    // 8*16*16*28 / 256

// -------------------------------------- merged prep (u pad+fp16 | w reorder+fp16)
__global__ __launch_bounds__(256) void prep_k(const float* __restrict__ u,
                                              const float* __restrict__ w,
                                              _Float16* __restrict__ u16,
                                              _Float16* __restrict__ w16) {
  if (blockIdx.x < PREP_U_BLOCKS) {
    int idx = blockIdx.x * 256 + threadIdx.x;
    int col = idx % 52;
    int t = idx / 52;
    int row = t % 52;
    t /= 52;                        // t = n*CIc + ci
    int h = row - 2, wc = col - 2;
    f16x8 hv;
#pragma unroll
    for (int di = 0; di < 8; ++di) {
      float val = 0.f;
      if (h >= 0 && h < Hh && wc >= 0 && wc < Ww)
        val = u[((size_t)t * DIc + di) * HW + h * Ww + wc];
      hv[di] = (_Float16)val;
    }
    *(f16x8*)(u16 + (size_t)idx * 8) = hv;
  } else {
    int idx = (blockIdx.x - PREP_U_BLOCKS) * 256 + threadIdx.x;
    int tap = idx % 28;
    int t = idx / 28;
    int dd = t % DOo;
    t /= DOo;
    int co = t % COo;
    int ci = t / COo;
    f16x8 hv;
#pragma unroll
    for (int di = 0; di < 8; ++di) {
      float val = 0.f;
      if (tap < 25)
        val = w[((size_t)(ci * 256 + co * 16 + dd)) * 200 + di * 25 + tap];
      hv[di] = (_Float16)val;
    }
    *(f16x8*)(w16 + ((size_t)(ci * COo + co) * DOo + dd) * 224 + tap * 8) = hv;
  }
}

// ---------------------------------------------------------------- MFMA conv
// Per (n,ci): C[256 (co,do), 2304 p] = W[256,224] x im2col(u)[224,2304], fp16.
// Block = (n, ci, pos-eighth): 256 thr / 4 waves; wave = 4 co (co0 = wv*4).
// One B-fragment LDS read feeds 4 MFMAs; plane staged 8x total (was 16x).
__global__ __launch_bounds__(256, 2) void conv_mfma_k(const _Float16* __restrict__ u16,
                                                      const _Float16* __restrict__ w16,
                                                      _Float16* __restrict__ uhat) {
  __shared__ _Float16 s_u[11 * 52 * 8];   // 9,152 B (row 10 = zeros)

  const int blk = blockIdx.x;            // 512 = n*8*8 + ci*8 + pe
  const int pe = blk & 7;                // pos-eighth: output rows pe*6 .. pe*6+5
  const int ci = (blk >> 3) & 7;
  const int n  = blk >> 6;
  const int tid = threadIdx.x;
  const int wv = tid >> 6, lane = tid & 63;
  const int l15 = lane & 15, l4 = lane >> 4;

  const _Float16* gu = u16 + ((size_t)(n * CIc + ci) * 2704 + pe * 6 * 52) * 8;
  for (int it = tid; it < 520; it += 256)
    *(f16x8*)(s_u + it * 8) = *(const f16x8*)(gu + it * 8);
  if (tid < 52) {
    f16x8 z = {0, 0, 0, 0, 0, 0, 0, 0};
    *(f16x8*)(s_u + (520 + tid) * 8) = z;
  }

  const int co0 = wv * 4;
  f16x8 a[4][7];
#pragma unroll
  for (int c = 0; c < 4; ++c) {
    const _Float16* wb = w16 + ((size_t)(ci * COo + co0 + c) * DOo + l15) * 224 + l4 * 8;
#pragma unroll
    for (int ks = 0; ks < 7; ++ks) a[c][ks] = *(const f16x8*)(wb + ks * 32);
  }
  __syncthreads();

  _Float16* ob = uhat + (size_t)((n * CIc + ci) * COo + co0) * (HW * 16);

  for (int chunk = 0; chunk < 6; ++chunk) {
    f32x4 acc[4][3];
#pragma unroll
    for (int c = 0; c < 4; ++c)
#pragma unroll
      for (int nt = 0; nt < 3; ++nt) {
        f32x4 z = {0.f, 0.f, 0.f, 0.f};
        acc[c][nt] = z;
      }
#pragma unroll
    for (int ks = 0; ks < 7; ++ks) {
      const int tap = ks * 4 + l4;       // 0..27 (25..27: zero weights)
      const int dy = tap / 5;            // 0..5
      const int dx = tap - dy * 5;
      const int row = chunk + dy;        // <= 10
#pragma unroll
      for (int nt = 0; nt < 3; ++nt) {
        const int col = nt * 16 + dx + l15;
        f16x8 bfrag = *(const f16x8*)(s_u + (row * 52 + col) * 8);
#pragma unroll
        for (int c = 0; c < 4; ++c)
          acc[c][nt] = __builtin_amdgcn_mfma_f32_16x16x32_f16(a[c][ks], bfrag, acc[c][nt], 0, 0, 0);
      }
    }
    // C frag: col = l15 = position, row = l4*4+j = do  -> f16x4 store
#pragma unroll
    for (int c = 0; c < 4; ++c)
#pragma unroll
      for (int nt = 0; nt < 3; ++nt) {
        int p = pe * 288 + chunk * 48 + nt * 16 + l15;
        f32x4 vv = acc[c][nt];
        f16x4 hv;
        hv[0] = (_Float16)vv[0]; hv[1] = (_Float16)vv[1];
        hv[2] = (_Float16)vv[2]; hv[3] = (_Float16)vv[3];
        *(f16x4*)(ob + (size_t)c * (HW * 16) + (size_t)p * 16 + l4 * 4) = hv;
      }
  }
}

// ----------------------------------------------------- routing stats (separable)
__global__ __launch_bounds__(256) void routing_stats_k(const float* __restrict__ b,
                                                       float* __restrict__ bmax,
                                                       float* __restrict__ isum) {
  __shared__ float m_lds[HW];
  __shared__ float t_lds[HW];
  const int blk = blockIdx.x;   // n*CIc + ci
  const int tid = threadIdx.x;
  const float* bp = b + (size_t)blk * COo * HW;

  for (int p = tid; p < HW; p += 256) {
    float m = -INFINITY;
    for (int co = 0; co < COo; ++co) m = fmaxf(m, bp[(size_t)co * HW + p]);
    m_lds[p] = m;
  }
  __syncthreads();
  for (int p = tid; p < HW; p += 256) {
    int h = p / Ww, w = p % Ww;
    float v = -INFINITY;
#pragma unroll
    for (int dx = -2; dx <= 2; ++dx) {
      int ww2 = w + dx;
      if (ww2 >= 0 && ww2 < Ww) v = fmaxf(v, m_lds[h * Ww + ww2]);
    }
    t_lds[p] = v;
  }
  __syncthreads();
  for (int p = tid; p < HW; p += 256) {
    int h = p / Ww, w = p % Ww;
    float bm = -INFINITY;
#pragma unroll
    for (int dy = -2; dy <= 2; ++dy) {
      int hh = h + dy;
      if (hh >= 0 && hh < Hh) bm = fmaxf(bm, t_lds[hh * Ww + w]);
    }
    bmax[(size_t)blk * HW + p] = bm;
    float cs = 0.f;
    for (int co = 0; co < COo; ++co)
      cs += __expf(bp[(size_t)co * HW + p] - bm);
    m_lds[p] = cs;
  }
  __syncthreads();
  for (int p = tid; p < HW; p += 256) {
    int h = p / Ww, w = p % Ww;
    float s = 0.f;
#pragma unroll
    for (int dx = -2; dx <= 2; ++dx) {
      int ww2 = w + dx;
      if (ww2 >= 0 && ww2 < Ww) s += m_lds[h * Ww + ww2];
    }
    t_lds[p] = s;
  }
  __syncthreads();
  for (int p = tid; p < HW; p += 256) {
    int h = p / Ww, w = p % Ww;
    float s = 0.f;
#pragma unroll
    for (int dy = -2; dy <= 2; ++dy) {
      int hh = h + dy;
      if (hh >= 0 && hh < Hh) s += t_lds[hh * Ww + w];
    }
    isum[(size_t)blk * HW + p] = 1.f / s;
  }
}

// ------------------------------------------- fused p + squash + b-update
// 4-way do split: thread handles 4 of 16 do (q = idx&3); quad cooperates via
// __shfl_xor(.,1)+(.,2). uh cvt to LIVE f32 regs at load (proven pattern).
// d0 (zb=1): closed-form r, no b/bmax/isum loads.
__global__ __launch_bounds__(256, 5) void fused_route_k(const float* __restrict__ b,
                                                        const float* __restrict__ bmax,
                                                        const float* __restrict__ isum,
                                                        const _Float16* __restrict__ uhat,
                                                        float* __restrict__ bout,
                                                        float* __restrict__ vout,
                                                        int zb, int last) {
  int idx = blockIdx.x * 256 + threadIdx.x;  // (((n*COo+co)*HW)+p)*4 + q
  int q   = idx & 3;
  int t0  = idx >> 2;
  int p  = t0 % HW;
  int t  = t0 / HW;
  int co = t % COo;
  int n  = t / COo;

  float bl[CIc], r[CIc];
  if (zb) {
    int h = p / Ww, w = p % Ww;
    int ch = min(h + 2, Hh - 1) - max(h - 2, 0) + 1;
    int cw = min(w + 2, Ww - 1) - max(w - 2, 0) + 1;
    float r0 = 1.f / (16.f * (float)(ch * cw));
#pragma unroll
    for (int ci = 0; ci < CIc; ++ci) { bl[ci] = 0.f; r[ci] = r0; }
  } else {
#pragma unroll
    for (int ci = 0; ci < CIc; ++ci) {
      int s = n * CIc + ci;
      bl[ci] = b[(size_t)(s * COo + co) * HW + p];
      r[ci]  = __expf(bl[ci] - bmax[(size_t)s * HW + p]) * isum[(size_t)s * HW + p];
    }
  }

  // 4 do per thread (q selects the f16x4 chunk); cvt to live f32 regs.
  float4 uh[CIc];
  float4 a0 = make_float4(0.f, 0.f, 0.f, 0.f);
#pragma unroll
  for (int ci = 0; ci < CIc; ++ci) {
    const f16x4* uhp = (const f16x4*)(uhat +
        ((size_t)((n * CIc + ci) * COo + co) * HW + p) * DOo + q * 4);
    f16x4 h0 = *uhp;
    uh[ci] = make_float4((float)h0[0], (float)h0[1], (float)h0[2], (float)h0[3]);
    float rc = r[ci];
    a0.x = fmaf(rc, uh[ci].x, a0.x); a0.y = fmaf(rc, uh[ci].y, a0.y);
    a0.z = fmaf(rc, uh[ci].z, a0.z); a0.w = fmaf(rc, uh[ci].w, a0.w);
  }

  float nsqp = a0.x*a0.x + a0.y*a0.y + a0.z*a0.z + a0.w*a0.w;
  float s1  = nsqp + __shfl_xor(nsqp, 1);
  float nsq = s1 + __shfl_xor(s1, 2);
  float scale = nsq / (1.f + nsq) / sqrtf(nsq + 1e-9f);
  a0.x *= scale; a0.y *= scale; a0.z *= scale; a0.w *= scale;

  if (last) {
    float* vp = vout + (size_t)(n * COo + co) * DOo * HW + (size_t)q * 4 * HW + p;
    vp[0*HW]=a0.x; vp[1*HW]=a0.y; vp[2*HW]=a0.z; vp[3*HW]=a0.w;
  } else {
#pragma unroll
    for (int ci = 0; ci < CIc; ++ci) {
      float dp = uh[ci].x*a0.x + uh[ci].y*a0.y + uh[ci].z*a0.z + uh[ci].w*a0.w;
      float d1 = dp + __shfl_xor(dp, 1);
      float dot = d1 + __shfl_xor(d1, 2);
      if (q == 0)
        bout[(size_t)((n * CIc + ci) * COo + co) * HW + p] = bl[ci] + dot;
    }
  }
}

// ------------------------------------------------------------------ launch
extern "C" void kernel_launch(void* const* d_in, const int* in_sizes, int n_in,
                              void* d_out, int out_size, void* d_ws, size_t ws_size,
                              hipStream_t stream) {
  const float* u = (const float*)d_in[0];
  const float* w = (const float*)d_in[1];
  float* out = (float*)d_out;
  char* wsb  = (char*)d_ws;

  _Float16*  uhat = (_Float16*)(wsb + OFFB_UHAT);
  float*     b    = (float*)(wsb + OFFB_B);
  float*     bm   = (float*)(wsb + OFFB_BM);
  float*     is   = (float*)(wsb + OFFB_IS);
  _Float16*  u16  = (_Float16*)(wsb + OFFB_U16);
  _Float16*  w16  = (_Float16*)(wsb + OFFB_W16);

  prep_k<<<PREP_U_BLOCKS + PREP_W_BLOCKS, 256, 0, stream>>>(u, w, u16, w16);
  conv_mfma_k<<<NN * CIc * 8, 256, 0, stream>>>(u16, w16, uhat);

  const int route_grid = (NN * COo * HW * 4) / 256;   // 4608

  // d = 0: closed-form r, no stats dispatch
  fused_route_k<<<route_grid, 256, 0, stream>>>(b, bm, is, uhat, b, out, 1, 0);

  // d = 1
  routing_stats_k<<<NN * CIc, 256, 0, stream>>>(b, bm, is);
  fused_route_k<<<route_grid, 256, 0, stream>>>(b, bm, is, uhat, b, out, 0, 0);

  // d = 2 -> final v straight to d_out
  routing_stats_k<<<NN * CIc, 256, 0, stream>>>(b, bm, is);
  fused_route_k<<<route_grid, 256, 0, stream>>>(b, bm, is, uhat, b, out, 0, 1);
}

// Round 11
// 92.211 us; speedup vs baseline: 1.9377x; 1.1988x over previous
//
#include <hip/hip_runtime.h>
#include <math.h>

// Problem constants
#define NN  8
#define CIc 8
#define DIc 8
#define Hh  48
#define Ww  48
#define COo 16
#define DOo 16
#define HW  2304      // 48*48

typedef _Float16 f16x8 __attribute__((ext_vector_type(8)));
typedef _Float16 f16x4 __attribute__((ext_vector_type(4)));
typedef float f32x4 __attribute__((ext_vector_type(4)));

// ---------------- workspace layout (byte offsets) ----------------
#define OFFB_UHAT 0
#define OFFB_B    75497472
#define OFFB_BM   84934656
#define OFFB_IS   85524480
#define OFFB_U16  86114304
#define OFFB_W16  88883200

#define PREP_U_BLOCKS 676    // 8*8*52*52 / 256
#define PREP_W_BLOCKS 224    // 8*16*16*28 / 256

// -------------------------------------- merged prep (u pad+fp16 | w reorder+fp16)
__global__ __launch_bounds__(256) void prep_k(const float* __restrict__ u,
                                              const float* __restrict__ w,
                                              _Float16* __restrict__ u16,
                                              _Float16* __restrict__ w16) {
  if (blockIdx.x < PREP_U_BLOCKS) {
    int idx = blockIdx.x * 256 + threadIdx.x;
    int col = idx % 52;
    int t = idx / 52;
    int row = t % 52;
    t /= 52;                        // t = n*CIc + ci
    int h = row - 2, wc = col - 2;
    f16x8 hv;
#pragma unroll
    for (int di = 0; di < 8; ++di) {
      float val = 0.f;
      if (h >= 0 && h < Hh && wc >= 0 && wc < Ww)
        val = u[((size_t)t * DIc + di) * HW + h * Ww + wc];
      hv[di] = (_Float16)val;
    }
    *(f16x8*)(u16 + (size_t)idx * 8) = hv;
  } else {
    int idx = (blockIdx.x - PREP_U_BLOCKS) * 256 + threadIdx.x;
    int tap = idx % 28;
    int t = idx / 28;
    int dd = t % DOo;
    t /= DOo;
    int co = t % COo;
    int ci = t / COo;
    f16x8 hv;
#pragma unroll
    for (int di = 0; di < 8; ++di) {
      float val = 0.f;
      if (tap < 25)
        val = w[((size_t)(ci * 256 + co * 16 + dd)) * 200 + di * 25 + tap];
      hv[di] = (_Float16)val;
    }
    *(f16x8*)(w16 + ((size_t)(ci * COo + co) * DOo + dd) * 224 + tap * 8) = hv;
  }
}

// ---------------------------------------------------------------- MFMA conv
// Per (n,ci): C[256 (co,do), 2304 p] = W[256,224] x im2col(u)[224,2304], fp16.
// Block = (n, ci, pos-eighth): 256 thr / 4 waves; wave = 4 co (co0 = wv*4).
__global__ __launch_bounds__(256, 2) void conv_mfma_k(const _Float16* __restrict__ u16,
                                                      const _Float16* __restrict__ w16,
                                                      _Float16* __restrict__ uhat) {
  __shared__ _Float16 s_u[11 * 52 * 8];   // 9,152 B (row 10 = zeros)

  const int blk = blockIdx.x;            // 512 = n*8*8 + ci*8 + pe
  const int pe = blk & 7;                // pos-eighth: output rows pe*6 .. pe*6+5
  const int ci = (blk >> 3) & 7;
  const int n  = blk >> 6;
  const int tid = threadIdx.x;
  const int wv = tid >> 6, lane = tid & 63;
  const int l15 = lane & 15, l4 = lane >> 4;

  const _Float16* gu = u16 + ((size_t)(n * CIc + ci) * 2704 + pe * 6 * 52) * 8;
  for (int it = tid; it < 520; it += 256)
    *(f16x8*)(s_u + it * 8) = *(const f16x8*)(gu + it * 8);
  if (tid < 52) {
    f16x8 z = {0, 0, 0, 0, 0, 0, 0, 0};
    *(f16x8*)(s_u + (520 + tid) * 8) = z;
  }

  const int co0 = wv * 4;
  f16x8 a[4][7];
#pragma unroll
  for (int c = 0; c < 4; ++c) {
    const _Float16* wb = w16 + ((size_t)(ci * COo + co0 + c) * DOo + l15) * 224 + l4 * 8;
#pragma unroll
    for (int ks = 0; ks < 7; ++ks) a[c][ks] = *(const f16x8*)(wb + ks * 32);
  }
  __syncthreads();

  _Float16* ob = uhat + (size_t)((n * CIc + ci) * COo + co0) * (HW * 16);

  for (int chunk = 0; chunk < 6; ++chunk) {
    f32x4 acc[4][3];
#pragma unroll
    for (int c = 0; c < 4; ++c)
#pragma unroll
      for (int nt = 0; nt < 3; ++nt) {
        f32x4 z = {0.f, 0.f, 0.f, 0.f};
        acc[c][nt] = z;
      }
#pragma unroll
    for (int ks = 0; ks < 7; ++ks) {
      const int tap = ks * 4 + l4;       // 0..27 (25..27: zero weights)
      const int dy = tap / 5;            // 0..5
      const int dx = tap - dy * 5;
      const int row = chunk + dy;        // <= 10
#pragma unroll
      for (int nt = 0; nt < 3; ++nt) {
        const int col = nt * 16 + dx + l15;
        f16x8 bfrag = *(const f16x8*)(s_u + (row * 52 + col) * 8);
#pragma unroll
        for (int c = 0; c < 4; ++c)
          acc[c][nt] = __builtin_amdgcn_mfma_f32_16x16x32_f16(a[c][ks], bfrag, acc[c][nt], 0, 0, 0);
      }
    }
#pragma unroll
    for (int c = 0; c < 4; ++c)
#pragma unroll
      for (int nt = 0; nt < 3; ++nt) {
        int p = pe * 288 + chunk * 48 + nt * 16 + l15;
        f32x4 vv = acc[c][nt];
        f16x4 hv;
        hv[0] = (_Float16)vv[0]; hv[1] = (_Float16)vv[1];
        hv[2] = (_Float16)vv[2]; hv[3] = (_Float16)vv[3];
        *(f16x4*)(ob + (size_t)c * (HW * 16) + (size_t)p * 16 + l4 * 4) = hv;
      }
  }
}

// ----------------------------------------------------- routing stats (banded)
// Block = (n*CIc+ci)*4 + band; band covers 12 output rows (+4-row halo each way).
// Staged: 20 rows. -inf pad for maxpool; cs=0 at OOB rows (zero-pad boxsum).
#define BROWS 12
#define SROWS 20
__global__ __launch_bounds__(256) void routing_stats_k(const float* __restrict__ b,
                                                       float* __restrict__ bmax,
                                                       float* __restrict__ isum) {
  __shared__ float m_lds[SROWS * Ww];
  __shared__ float t_lds[SROWS * Ww];
  const int blk  = blockIdx.x;
  const int band = blk & 3;
  const int s    = blk >> 2;            // n*CIc + ci
  const int r0   = band * BROWS;
  const int tid  = threadIdx.x;
  const float* bp = b + (size_t)s * COo * HW;

  // phase A: m[sr][c] = max_co b at global row gr = r0-4+sr
  for (int i = tid; i < SROWS * Ww; i += 256) {
    int sr = i / Ww, c = i % Ww;
    int gr = r0 - 4 + sr;
    float m = -INFINITY;
    if (gr >= 0 && gr < Hh) {
      int p = gr * Ww + c;
      for (int co = 0; co < COo; ++co) m = fmaxf(m, bp[(size_t)co * HW + p]);
    }
    m_lds[i] = m;
  }
  __syncthreads();
  // phase B: row-max (cols clamped)
  for (int i = tid; i < SROWS * Ww; i += 256) {
    int sr = i / Ww, c = i % Ww;
    float v = -INFINITY;
#pragma unroll
    for (int dx = -2; dx <= 2; ++dx) {
      int cc = c + dx;
      if (cc >= 0 && cc < Ww) v = fmaxf(v, m_lds[sr * Ww + cc]);
    }
    t_lds[i] = v;
  }
  __syncthreads();
  // phase C: col-max -> bm for sr in 2..17; write bmax for output rows; cs -> m_lds
  for (int i = tid; i < 16 * Ww; i += 256) {
    int sr = i / Ww + 2, c = i % Ww;
    float bm = fmaxf(fmaxf(fmaxf(t_lds[(sr-2)*Ww+c], t_lds[(sr-1)*Ww+c]), t_lds[sr*Ww+c]),
                     fmaxf(t_lds[(sr+1)*Ww+c], t_lds[(sr+2)*Ww+c]));
    int gr = r0 - 4 + sr;
    float cs = 0.f;
    if (gr >= 0 && gr < Hh) {
      int p = gr * Ww + c;
      if (sr >= 4 && sr < 16) bmax[(size_t)s * HW + p] = bm;
      for (int co = 0; co < COo; ++co)
        cs += __expf(bp[(size_t)co * HW + p] - bm);
    }
    m_lds[sr * Ww + c] = cs;
  }
  __syncthreads();
  // phase D: row-sum of cs for sr 2..17 -> t_lds
  for (int i = tid; i < 16 * Ww; i += 256) {
    int sr = i / Ww + 2, c = i % Ww;
    float sum = 0.f;
#pragma unroll
    for (int dx = -2; dx <= 2; ++dx) {
      int cc = c + dx;
      if (cc >= 0 && cc < Ww) sum += m_lds[sr * Ww + cc];
    }
    t_lds[sr * Ww + c] = sum;
  }
  __syncthreads();
  // phase E: col-sum for output rows sr 4..15 -> isum
  for (int i = tid; i < BROWS * Ww; i += 256) {
    int sr = i / Ww + 4, c = i % Ww;
    int gr = r0 - 4 + sr;
    float sum = t_lds[(sr-2)*Ww+c] + t_lds[(sr-1)*Ww+c] + t_lds[sr*Ww+c]
              + t_lds[(sr+1)*Ww+c] + t_lds[(sr+2)*Ww+c];
    isum[(size_t)s * HW + gr * Ww + c] = 1.f / sum;
  }
}

// ------------------------------------------- fused p + squash + b-update
// R9-exact route: 2-way do split (16B f16x8 uh loads), uh cvt to LIVE f32 regs,
// pair cooperates via __shfl_xor(.,1). d0 (zb=1): closed-form r, no stats reads.
__global__ __launch_bounds__(256, 4) void fused_route_k(const float* __restrict__ b,
                                                        const float* __restrict__ bmax,
                                                        const float* __restrict__ isum,
                                                        const _Float16* __restrict__ uhat,
                                                        float* __restrict__ bout,
                                                        float* __restrict__ vout,
                                                        int zb, int last) {
  int idx  = blockIdx.x * 256 + threadIdx.x;  // (((n*COo+co)*HW)+p)*2 + half
  int half = idx & 1;
  int t0   = idx >> 1;
  int p  = t0 % HW;
  int t  = t0 / HW;
  int co = t % COo;
  int n  = t / COo;

  float bl[CIc], r[CIc];
  if (zb) {
    int h = p / Ww, w = p % Ww;
    int ch = min(h + 2, Hh - 1) - max(h - 2, 0) + 1;
    int cw = min(w + 2, Ww - 1) - max(w - 2, 0) + 1;
    float r0 = 1.f / (16.f * (float)(ch * cw));
#pragma unroll
    for (int ci = 0; ci < CIc; ++ci) { bl[ci] = 0.f; r[ci] = r0; }
  } else {
#pragma unroll
    for (int ci = 0; ci < CIc; ++ci) {
      int s = n * CIc + ci;
      bl[ci] = b[(size_t)(s * COo + co) * HW + p];
      r[ci]  = __expf(bl[ci] - bmax[(size_t)s * HW + p]) * isum[(size_t)s * HW + p];
    }
  }

  float4 uh[CIc][2];
  float4 a0 = make_float4(0.f, 0.f, 0.f, 0.f);
  float4 a1 = a0;
#pragma unroll
  for (int ci = 0; ci < CIc; ++ci) {
    const f16x8* uhp = (const f16x8*)(uhat +
        ((size_t)((n * CIc + ci) * COo + co) * HW + p) * DOo + half * 8);
    f16x8 h0 = uhp[0];
    uh[ci][0] = make_float4((float)h0[0], (float)h0[1], (float)h0[2], (float)h0[3]);
    uh[ci][1] = make_float4((float)h0[4], (float)h0[5], (float)h0[6], (float)h0[7]);
    float rc = r[ci];
    a0.x = fmaf(rc, uh[ci][0].x, a0.x); a0.y = fmaf(rc, uh[ci][0].y, a0.y);
    a0.z = fmaf(rc, uh[ci][0].z, a0.z); a0.w = fmaf(rc, uh[ci][0].w, a0.w);
    a1.x = fmaf(rc, uh[ci][1].x, a1.x); a1.y = fmaf(rc, uh[ci][1].y, a1.y);
    a1.z = fmaf(rc, uh[ci][1].z, a1.z); a1.w = fmaf(rc, uh[ci][1].w, a1.w);
  }

  float nsqp = a0.x*a0.x + a0.y*a0.y + a0.z*a0.z + a0.w*a0.w
             + a1.x*a1.x + a1.y*a1.y + a1.z*a1.z + a1.w*a1.w;
  float nsq = nsqp + __shfl_xor(nsqp, 1);
  float scale = nsq / (1.f + nsq) / sqrtf(nsq + 1e-9f);
  a0.x *= scale; a0.y *= scale; a0.z *= scale; a0.w *= scale;
  a1.x *= scale; a1.y *= scale; a1.z *= scale; a1.w *= scale;

  if (last) {
    float* vp = vout + (size_t)(n * COo + co) * DOo * HW + (size_t)half * 8 * HW + p;
    vp[0*HW]=a0.x; vp[1*HW]=a0.y; vp[2*HW]=a0.z; vp[3*HW]=a0.w;
    vp[4*HW]=a1.x; vp[5*HW]=a1.y; vp[6*HW]=a1.z; vp[7*HW]=a1.w;
  } else {
#pragma unroll
    for (int ci = 0; ci < CIc; ++ci) {
      float dp = uh[ci][0].x*a0.x + uh[ci][0].y*a0.y + uh[ci][0].z*a0.z + uh[ci][0].w*a0.w
               + uh[ci][1].x*a1.x + uh[ci][1].y*a1.y + uh[ci][1].z*a1.z + uh[ci][1].w*a1.w;
      float dot = dp + __shfl_xor(dp, 1);
      if (half == 0)
        bout[(size_t)((n * CIc + ci) * COo + co) * HW + p] = bl[ci] + dot;
    }
  }
}

// ------------------------------------------------------------------ launch
extern "C" void kernel_launch(void* const* d_in, const int* in_sizes, int n_in,
                              void* d_out, int out_size, void* d_ws, size_t ws_size,
                              hipStream_t stream) {
  const float* u = (const float*)d_in[0];
  const float* w = (const float*)d_in[1];
  float* out = (float*)d_out;
  char* wsb  = (char*)d_ws;

  _Float16*  uhat = (_Float16*)(wsb + OFFB_UHAT);
  float*     b    = (float*)(wsb + OFFB_B);
  float*     bm   = (float*)(wsb + OFFB_BM);
  float*     is   = (float*)(wsb + OFFB_IS);
  _Float16*  u16  = (_Float16*)(wsb + OFFB_U16);
  _Float16*  w16  = (_Float16*)(wsb + OFFB_W16);

  prep_k<<<PREP_U_BLOCKS + PREP_W_BLOCKS, 256, 0, stream>>>(u, w, u16, w16);
  conv_mfma_k<<<NN * CIc * 8, 256, 0, stream>>>(u16, w16, uhat);

  const int route_grid = (NN * COo * HW * 2) / 256;   // 2304
  const int stats_grid = NN * CIc * 4;                // 256

  // d = 0: closed-form r, no stats dispatch
  fused_route_k<<<route_grid, 256, 0, stream>>>(b, bm, is, uhat, b, out, 1, 0);

  // d = 1
  routing_stats_k<<<stats_grid, 256, 0, stream>>>(b, bm, is);
  fused_route_k<<<route_grid, 256, 0, stream>>>(b, bm, is, uhat, b, out, 0, 0);

  // d = 2 -> final v straight to d_out
  routing_stats_k<<<stats_grid, 256, 0, stream>>>(b, bm, is);
  fused_route_k<<<route_grid, 256, 0, stream>>>(b, bm, is, uhat, b, out, 0, 1);
}